// Round 1
// baseline (2577.419 us; speedup 1.0000x reference)
//
#include <hip/hip_runtime.h>
#include <cstdint>
#include <math.h>

// ---------------- constants ----------------
// B=16, L=12, N=512, RC=DC=32, SC=256, EC=512, OUT=12, RECEPTIVE=13
// x buffers layout: [b][c][t][n], n contiguous, t stride 512, c stride 13*512
#define NB 16
#define NN 512
#define RC 32
#define RECEP 13
#define EDIM 152
#define HIDD 128
#define BNSCALE 0.9999950000374998f

__device__ __forceinline__ uint32_t rotl32(uint32_t x, int d){ return (x<<d)|(x>>(32-d)); }

__device__ __forceinline__ void threefry2x32(uint32_t& x0, uint32_t& x1){
  const uint32_t ks0=0u, ks1=42u, ks2=42u^0x1BD11BDAu;
  x0+=ks0; x1+=ks1;
  x0+=x1; x1=rotl32(x1,13); x1^=x0;
  x0+=x1; x1=rotl32(x1,15); x1^=x0;
  x0+=x1; x1=rotl32(x1,26); x1^=x0;
  x0+=x1; x1=rotl32(x1, 6); x1^=x0;
  x0+=ks1; x1+=ks2+1u;
  x0+=x1; x1=rotl32(x1,17); x1^=x0;
  x0+=x1; x1=rotl32(x1,29); x1^=x0;
  x0+=x1; x1=rotl32(x1,16); x1^=x0;
  x0+=x1; x1=rotl32(x1,24); x1^=x0;
  x0+=ks2; x1+=ks0+2u;
  x0+=x1; x1=rotl32(x1,13); x1^=x0;
  x0+=x1; x1=rotl32(x1,15); x1^=x0;
  x0+=x1; x1=rotl32(x1,26); x1^=x0;
  x0+=x1; x1=rotl32(x1, 6); x1^=x0;
  x0+=ks0; x1+=ks1+3u;
  x0+=x1; x1=rotl32(x1,17); x1^=x0;
  x0+=x1; x1=rotl32(x1,29); x1^=x0;
  x0+=x1; x1=rotl32(x1,16); x1^=x0;
  x0+=x1; x1=rotl32(x1,24); x1^=x0;
  x0+=ks1; x1+=ks2+4u;
  x0+=x1; x1=rotl32(x1,13); x1^=x0;
  x0+=x1; x1=rotl32(x1,15); x1^=x0;
  x0+=x1; x1=rotl32(x1,26); x1^=x0;
  x0+=x1; x1=rotl32(x1, 6); x1^=x0;
  x0+=ks2; x1+=ks0+5u;
}

// ---------------- start conv (with left pad 1) ----------------
__global__ void k_start(const float* __restrict__ hist, const float* __restrict__ sw,
                        const float* __restrict__ sb, float* __restrict__ x){
  int idx = blockIdx.x*256 + threadIdx.x;          // ((b*32+o)*13+t)*512+n
  int n = idx & 511; int r = idx >> 9;
  int t = r % 13; r /= 13; int o = r & 31; int b = r >> 5;
  float acc = sb[o];
  if (t > 0){
    const float* h = hist + ((size_t)(b*12 + (t-1))*512 + n)*3;
    acc += h[0]*sw[o*2+0] + h[1]*sw[o*2+1];
  }
  x[idx] = acc;
}

// ---------------- nodevec graph ----------------
__global__ void k_gw_mm(const float* __restrict__ nv1, const float* __restrict__ nv2,
                        float* __restrict__ gw){
  int idx = blockIdx.x*256+threadIdx.x;            // v*512+w
  int w = idx & 511, v = idx >> 9;
  float acc=0.f;
  #pragma unroll
  for (int k=0;k<64;k++) acc += nv1[v*64+k]*nv2[k*512+w];
  gw[idx]=acc;
}

__global__ void k_gw_sm(float* __restrict__ gw){
  int v = blockIdx.x; int tid=threadIdx.x;
  float a0 = fmaxf(gw[v*512+tid],0.f), a1=fmaxf(gw[v*512+256+tid],0.f);
  __shared__ float red[256];
  red[tid]=fmaxf(a0,a1); __syncthreads();
  for(int s=128;s>0;s>>=1){ if(tid<s) red[tid]=fmaxf(red[tid],red[tid+s]); __syncthreads(); }
  float m = red[0]; __syncthreads();
  float e0=expf(a0-m), e1=expf(a1-m);
  red[tid]=e0+e1; __syncthreads();
  for(int s=128;s>0;s>>=1){ if(tid<s) red[tid]+=red[tid+s]; __syncthreads(); }
  float inv = 1.0f/red[0];
  gw[v*512+tid]=e0*inv; gw[v*512+256+tid]=e1*inv;
}

// ---------------- embedding: rfft |.| @ Ex1, node1, TiD, DiW ----------------
__global__ void k_embed(const float* __restrict__ hist, const float* __restrict__ Ex1,
                        const float* __restrict__ node1, const float* __restrict__ TiD,
                        const float* __restrict__ DiW, float* __restrict__ e){
  int row = blockIdx.x; int b = row >> 9; int n = row & 511;
  int tid = threadIdx.x;                            // 64 threads
  __shared__ float fr[7];
  if (tid < 7){
    float re=0.f, im=0.f;
    for (int l=0;l<12;l++){
      float v = hist[((size_t)(b*12+l)*512+n)*3];
      float ang = -2.0f*3.14159265358979323846f*(float)(tid*l)/12.0f;
      re += v*cosf(ang); im += v*sinf(ang);
    }
    fr[tid]=sqrtf(re*re+im*im);
  }
  __syncthreads();
  float* er = e + (size_t)row*EDIM;
  float acc=0.f;
  #pragma unroll
  for (int f=0;f<7;f++) acc += fr[f]*Ex1[f*64+tid];
  er[tid]=acc;
  er[64+tid]=node1[n*64+tid];
  if (tid<12){
    int it = (int)(hist[((size_t)(b*12+11)*512+n)*3+1]*288.0f);
    int id = (int)(hist[((size_t)(b*12+11)*512+n)*3+2]*7.0f);
    er[128+tid]=TiD[it*12+tid];
    er[140+tid]=DiW[id*12+tid];
  }
}

// ---------------- adp = e @ Wd[n] ----------------
__global__ void k_adp(const float* __restrict__ e, const float* __restrict__ Wd,
                      float* __restrict__ adp){
  int row=blockIdx.x; int n=row&511; int tid=threadIdx.x;  // 128 threads
  __shared__ float es[EDIM];
  es[tid]=e[(size_t)row*EDIM+tid];
  if(tid<24) es[128+tid]=e[(size_t)row*EDIM+128+tid];
  __syncthreads();
  const float* w = Wd + (size_t)n*EDIM*HIDD;
  float acc=0.f;
  for(int q=0;q<EDIM;q++) acc += es[q]*w[q*HIDD+tid];
  adp[(size_t)row*HIDD+tid]=acc;
}

// ---------------- layernorm over (n,k) per batch ----------------
__global__ void k_lnstats(const float* __restrict__ adp, float* __restrict__ stats){
  int b=blockIdx.x, tid=threadIdx.x;
  const float* p = adp + (size_t)b*65536;
  double s=0.0, s2=0.0;
  for(int i=tid;i<65536;i+=256){ float v=p[i]; s+=v; s2+=(double)v*v; }
  __shared__ double rs[256], rs2[256];
  rs[tid]=s; rs2[tid]=s2; __syncthreads();
  for(int k=128;k>0;k>>=1){ if(tid<k){rs[tid]+=rs[tid+k]; rs2[tid]+=rs2[tid+k];} __syncthreads(); }
  if(tid==0){ double mu=rs[0]/65536.0; double var=rs2[0]/65536.0 - mu*mu;
    stats[b*2]=(float)mu; stats[b*2+1]=(float)(1.0/sqrt(var+1e-8)); }
}

__global__ void k_lnapply(float* __restrict__ adp, const float* __restrict__ stats){
  int idx=blockIdx.x*256+threadIdx.x;              // 1,048,576
  int b = idx>>16;
  adp[idx]=(adp[idx]-stats[2*b])*stats[2*b+1];
}

// ---------------- t = adp @ Wxabs ----------------
__global__ void k_xw(const float* __restrict__ adp, const float* __restrict__ Wx,
                     float* __restrict__ t){
  int row=blockIdx.x; int tid=threadIdx.x;         // 128 threads
  __shared__ float as[HIDD];
  as[tid]=adp[(size_t)row*HIDD+tid]; __syncthreads();
  float acc=0.f;
  #pragma unroll 8
  for(int k=0;k<HIDD;k++) acc += as[k]*Wx[k*HIDD+tid];
  t[(size_t)row*HIDD+tid]=acc;
}

// ---------------- adj = relu(t @ adp^T) per batch (NT GEMM) ----------------
__global__ __launch_bounds__(256) void k_adjmm(const float* __restrict__ T,
                        const float* __restrict__ P, float* __restrict__ adj){
  int b = blockIdx.z;
  int n0 = blockIdx.y*32, m0 = blockIdx.x*64;
  const float* Tb = T + (size_t)b*512*HIDD;
  const float* Pb = P + (size_t)b*512*HIDD;
  __shared__ float Ts[32][33];
  __shared__ float Ps[64][33];
  int tid=threadIdx.x; int tx=tid&15, ty=tid>>4;
  float acc[2][4]={};
  for(int k0=0;k0<HIDD;k0+=32){
    for(int q=0;q<4;q++){ int idx=tid+q*256; int r=idx>>5, kk=idx&31; Ts[r][kk]=Tb[(size_t)(n0+r)*HIDD+k0+kk]; }
    for(int q=0;q<8;q++){ int idx=tid+q*256; int r=idx>>5, kk=idx&31; Ps[r][kk]=Pb[(size_t)(m0+r)*HIDD+k0+kk]; }
    __syncthreads();
    #pragma unroll
    for(int kk=0;kk<32;kk++){
      float t0=Ts[ty][kk], t1=Ts[ty+16][kk];
      float p0=Ps[tx*4+0][kk], p1=Ps[tx*4+1][kk], p2=Ps[tx*4+2][kk], p3=Ps[tx*4+3][kk];
      acc[0][0]+=t0*p0; acc[0][1]+=t0*p1; acc[0][2]+=t0*p2; acc[0][3]+=t0*p3;
      acc[1][0]+=t1*p0; acc[1][1]+=t1*p1; acc[1][2]+=t1*p2; acc[1][3]+=t1*p3;
    }
    __syncthreads();
  }
  for(int i2=0;i2<2;i2++){
    int n=n0+ty+16*i2;
    float4 o4=make_float4(fmaxf(acc[i2][0],0.f),fmaxf(acc[i2][1],0.f),
                          fmaxf(acc[i2][2],0.f),fmaxf(acc[i2][3],0.f));
    *(float4*)&adj[((size_t)b*512+n)*512+m0+tx*4]=o4;
  }
}

// ---------------- top-20 (jax threefry noise) + mask + softmax, *0.5 ----------------
__global__ void k_topk(float* __restrict__ adj){
  const int row = blockIdx.x;       // b*512+n
  const int tid = threadIdx.x;      // 64
  const uint32_t halfn = 2097152u;
  float a[8], v[8];
  const bool lowhalf = row < 4096;
  #pragma unroll
  for(int k=0;k<8;k++){
    int m = k*64+tid;
    uint32_t i = (uint32_t)row*512u + (uint32_t)m;
    uint32_t c0 = lowhalf ? i : i - halfn;
    uint32_t x0=c0, x1=c0+halfn;
    threefry2x32(x0,x1);
    uint32_t bits = lowhalf ? x0 : x1;
    float u = __uint_as_float((bits>>9)|0x3f800000u)-1.0f;
    a[k]=adj[(size_t)row*512+m];
    v[k]=a[k]+0.01f*u;
  }
  unsigned selmask=0u;
  for(int it=0; it<20; it++){
    float best=-1e30f; int bi=0x7fffffff;
    #pragma unroll
    for(int k=0;k<8;k++){
      if(!((selmask>>k)&1u)){
        int m=k*64+tid;
        if(v[k]>best || (v[k]==best && m<bi)){best=v[k]; bi=m;}
      }
    }
    #pragma unroll
    for(int off=32; off>=1; off>>=1){
      float ov=__shfl_xor(best,off); int oi=__shfl_xor(bi,off);
      if(ov>best || (ov==best && oi<bi)){best=ov; bi=oi;}
    }
    if((bi&63)==tid) selmask |= 1u<<(bi>>6);
  }
  float M=0.f;
  #pragma unroll
  for(int k=0;k<8;k++) if((selmask>>k)&1u) M=fmaxf(M,a[k]);
  #pragma unroll
  for(int off=32;off>=1;off>>=1) M=fmaxf(M,__shfl_xor(M,off));
  float S=0.f;
  #pragma unroll
  for(int k=0;k<8;k++) S += expf((((selmask>>k)&1u)? a[k]:0.f) - M);
  #pragma unroll
  for(int off=32;off>=1;off>>=1) S += __shfl_xor(S,off);
  float inv = 0.5f/S;   // fold A_COEF=0.5 into stored support
  #pragma unroll
  for(int k=0;k<8;k++){
    int m=k*64+tid;
    adj[(size_t)row*512+m] = expf((((selmask>>k)&1u)? a[k]:0.f)-M)*inv;
  }
}

// ---------------- dilated causal conv pair -> tanh*sigmoid ----------------
__global__ void k_tconv(const float* __restrict__ x, const float* __restrict__ fw,
                        const float* __restrict__ fb, const float* __restrict__ gw,
                        const float* __restrict__ gb, float* __restrict__ out,
                        int d, int lout){
  int n = blockIdx.x*256+threadIdx.x;
  int t = blockIdx.y;
  int z = blockIdx.z; int o = z&31, b = z>>5;
  const float* xb = x + ((size_t)b*32*RECEP + t)*512 + n;
  float f = fb[o], g = gb[o];
  #pragma unroll
  for(int c=0;c<32;c++){
    float lo = xb[(size_t)c*RECEP*512];
    float hi = xb[(size_t)c*RECEP*512 + (size_t)d*512];
    float w0f=fw[(o*32+c)*2], w1f=fw[(o*32+c)*2+1];
    float w0g=gw[(o*32+c)*2], w1g=gw[(o*32+c)*2+1];
    f += lo*w0f + hi*w1f;
    g += lo*w0g + hi*w1g;
  }
  out[((size_t)(b*32+o)*RECEP+t)*512+n] = tanhf(f) * (1.0f/(1.0f+expf(-g)));
}

// ---------------- skip accumulation (last timestep only) ----------------
__global__ void k_skipacc(const float* __restrict__ fg, const float* __restrict__ sw,
                          const float* __restrict__ sb, float* __restrict__ skip, int lout){
  int n = blockIdx.x*256+threadIdx.x;
  int s = blockIdx.y; int b = blockIdx.z;
  float acc = sb[s];
  const float* xb = fg + ((size_t)b*32*RECEP + (lout-1))*512 + n;
  #pragma unroll
  for(int c=0;c<32;c++) acc += sw[s*32+c]*xb[(size_t)c*RECEP*512];
  skip[((size_t)b*256+s)*512+n] += acc;
}

// ---------------- nconv: Y[(c,t) rows] = X @ A  (A 2D or per-batch) ----------------
__global__ __launch_bounds__(256) void k_nconv(const float* __restrict__ X,
                        const float* __restrict__ A, float* __restrict__ Y,
                        int lout, int batchedA){
  int b = blockIdx.z;
  int w0 = blockIdx.x*64;
  int R0 = blockIdx.y*32;
  const float* Ab = A + (batchedA ? (size_t)b*512*512 : 0);
  __shared__ int rb[32];
  __shared__ float Xs[32][33];
  __shared__ float As[32][64];
  int tid=threadIdx.x;
  if(tid<32){ int R=R0+tid; int c=R/lout; int t=R-c*lout; rb[tid]=((b*32+c)*RECEP+t)*512; }
  __syncthreads();
  int tx=tid&15, ty=tid>>4;
  float acc[2][4]={};
  for(int k0=0;k0<512;k0+=32){
    for(int q=0;q<4;q++){ int idx=tid+q*256; int r=idx>>5, kk=idx&31; Xs[r][kk]=X[(size_t)rb[r]+k0+kk]; }
    for(int q=0;q<8;q++){ int idx=tid+q*256; int r=idx>>6, ww=idx&63; As[r][ww]=Ab[(size_t)(k0+r)*512+w0+ww]; }
    __syncthreads();
    #pragma unroll
    for(int kk=0;kk<32;kk++){
      float x0v=Xs[ty][kk], x1v=Xs[ty+16][kk];
      float4 a4=*(float4*)&As[kk][tx*4];
      acc[0][0]+=x0v*a4.x; acc[0][1]+=x0v*a4.y; acc[0][2]+=x0v*a4.z; acc[0][3]+=x0v*a4.w;
      acc[1][0]+=x1v*a4.x; acc[1][1]+=x1v*a4.y; acc[1][2]+=x1v*a4.z; acc[1][3]+=x1v*a4.w;
    }
    __syncthreads();
  }
  #pragma unroll
  for(int i2=0;i2<2;i2++){
    int r=ty+16*i2;
    *(float4*)&Y[(size_t)rb[r]+w0+tx*4] = make_float4(acc[i2][0],acc[i2][1],acc[i2][2],acc[i2][3]);
  }
}

// ---------------- gcn 1x1 accumulation (one 32-chan group) ----------------
__global__ void k_acc(const float* __restrict__ part, const float* __restrict__ gw,
                      const float* __restrict__ gb, float* __restrict__ xout, int initf){
  int n = blockIdx.x*256+threadIdx.x;
  int t = blockIdx.y;
  int z = blockIdx.z; int o=z&31, b=z>>5;
  size_t ofs=((size_t)(b*32+o)*RECEP+t)*512+n;
  float acc = initf ? gb[o] : xout[ofs];
  const float* pb = part + ((size_t)b*32*RECEP + t)*512 + n;
  #pragma unroll
  for(int c=0;c<32;c++) acc += gw[o*160+c]*pb[(size_t)c*RECEP*512];
  xout[ofs]=acc;
}

// ---------------- last group + residual + bn scale ----------------
__global__ void k_final(const float* __restrict__ part, const float* __restrict__ gw,
                        const float* __restrict__ xout, const float* __restrict__ xres,
                        float* __restrict__ xnew, int d){
  int n = blockIdx.x*256+threadIdx.x;
  int t = blockIdx.y;
  int z = blockIdx.z; int o=z&31, b=z>>5;
  size_t ofs=((size_t)(b*32+o)*RECEP+t)*512+n;
  float acc=xout[ofs];
  const float* pb = part + ((size_t)b*32*RECEP + t)*512 + n;
  #pragma unroll
  for(int c=0;c<32;c++) acc += gw[o*160+c]*pb[(size_t)c*RECEP*512];
  acc += xres[((size_t)(b*32+o)*RECEP+t+d)*512+n];
  xnew[ofs]=acc*BNSCALE;
}

// ---------------- end convs ----------------
__global__ void k_end1(const float* __restrict__ skip, const float* __restrict__ w,
                       const float* __restrict__ bias, float* __restrict__ h){
  int n = blockIdx.x*256+threadIdx.x; int e2=blockIdx.y; int b=blockIdx.z;
  float acc=bias[e2];
  const float* sb_=skip + (size_t)b*256*512 + n;
  #pragma unroll 8
  for(int s=0;s<256;s++) acc += w[e2*256+s]*fmaxf(sb_[(size_t)s*512],0.f);
  h[((size_t)b*512+e2)*512+n]=fmaxf(acc,0.f);
}

__global__ void k_end2(const float* __restrict__ h, const float* __restrict__ w,
                       const float* __restrict__ bias, float* __restrict__ out){
  int n = blockIdx.x*256+threadIdx.x; int o=blockIdx.y; int b=blockIdx.z;
  float acc=bias[o];
  const float* hb=h + (size_t)b*512*512 + n;
  #pragma unroll 8
  for(int e=0;e<512;e++) acc += w[o*512+e]*hb[(size_t)e*512];
  out[((size_t)b*12+o)*512+n]=acc;
}

extern "C" void kernel_launch(void* const* d_in, const int* in_sizes, int n_in,
                              void* d_out, int out_size, void* d_ws, size_t ws_size,
                              hipStream_t stream) {
  (void)in_sizes; (void)n_in; (void)out_size;
  const float* hist   =(const float*)d_in[0];
  const float* start_w=(const float*)d_in[1];
  const float* start_b=(const float*)d_in[2];
  const float* filt_w =(const float*)d_in[3];
  const float* filt_b =(const float*)d_in[4];
  const float* gate_w =(const float*)d_in[5];
  const float* gate_b =(const float*)d_in[6];
  const float* skip_w =(const float*)d_in[7];
  const float* skip_b =(const float*)d_in[8];
  const float* gconv_w=(const float*)d_in[9];
  const float* gconv_b=(const float*)d_in[10];
  const float* end1_w =(const float*)d_in[11];
  const float* end1_b =(const float*)d_in[12];
  const float* end2_w =(const float*)d_in[13];
  const float* end2_b =(const float*)d_in[14];
  const float* Ex1    =(const float*)d_in[15];
  const float* node1  =(const float*)d_in[16];
  const float* Wd     =(const float*)d_in[17];
  const float* Wxabs  =(const float*)d_in[18];
  const float* TiD    =(const float*)d_in[19];
  const float* DiW    =(const float*)d_in[20];
  const float* nv1    =(const float*)d_in[21];
  const float* nv2    =(const float*)d_in[22];

  float* W=(float*)d_ws;
  const size_t BUFSZ=(size_t)16*32*13*512;       // 3,407,872 floats
  float* xA=W;
  float* xB=W+BUFSZ;
  float* xC=W+2*BUFSZ;
  float* xD=W+3*BUFSZ;
  float* xE=W+4*BUFSZ;
  float* skip=W+5*BUFSZ;                          // 16*256*512
  float* adjb=skip+(size_t)16*256*512;            // 16*512*512
  float* gwb =adjb+(size_t)16*512*512;            // 512*512
  float* stats=gwb+(size_t)512*512;               // 32
  const size_t needed=( (size_t)(stats - W) + 32 )*sizeof(float);
  if (ws_size < needed) return;                   // fail safe, avoid corruption

  hipMemsetAsync(skip, 0, (size_t)16*256*512*sizeof(float), stream);

  k_start<<<dim3(13312),dim3(256),0,stream>>>(hist,start_w,start_b,xA);
  k_gw_mm<<<dim3(1024),dim3(256),0,stream>>>(nv1,nv2,gwb);
  k_gw_sm<<<dim3(512),dim3(256),0,stream>>>(gwb);
  k_embed<<<dim3(8192),dim3(64),0,stream>>>(hist,Ex1,node1,TiD,DiW,xC);
  k_adp<<<dim3(8192),dim3(128),0,stream>>>(xC,Wd,xD);
  k_lnstats<<<dim3(16),dim3(256),0,stream>>>(xD,stats);
  k_lnapply<<<dim3(4096),dim3(256),0,stream>>>(xD,stats);
  k_xw<<<dim3(8192),dim3(128),0,stream>>>(xD,Wxabs,xE);
  k_adjmm<<<dim3(8,16,16),dim3(256),0,stream>>>(xE,xD,adjb);
  k_topk<<<dim3(8192),dim3(64),0,stream>>>(adjb);

  const int lin[8]={13,12,10,9,7,6,4,3};
  const int dil[8]={1,2,1,2,1,2,1,2};
  float* xcur=xA; float* alt=xB;
  for(int i=0;i<8;i++){
    int d=dil[i], lo=lin[i]-d;
    const float* fw=filt_w+(size_t)i*2048; const float* fb2=filt_b+i*32;
    const float* gw2=gate_w+(size_t)i*2048; const float* gb2=gate_b+i*32;
    const float* sw=skip_w+(size_t)i*8192;  const float* sb2=skip_b+i*256;
    const float* gcw=gconv_w+(size_t)i*32*160; const float* gcb=gconv_b+i*32;

    k_tconv<<<dim3(2,lo,512),dim3(256),0,stream>>>(xcur,fw,fb2,gw2,gb2,alt,d,lo);
    k_skipacc<<<dim3(2,256,16),dim3(256),0,stream>>>(alt,sw,sb2,skip,lo);
    // group 0: x itself (init with bias)
    k_acc<<<dim3(2,lo,512),dim3(256),0,stream>>>(alt,gcw+0,gcb,xE,1);
    // support 1 chain (gwadp)
    k_nconv<<<dim3(8,lo,16),dim3(256),0,stream>>>(alt,gwb,xC,lo,0);
    k_acc<<<dim3(2,lo,512),dim3(256),0,stream>>>(xC,gcw+32,gcb,xE,0);
    k_nconv<<<dim3(8,lo,16),dim3(256),0,stream>>>(xC,gwb,xD,lo,0);
    k_acc<<<dim3(2,lo,512),dim3(256),0,stream>>>(xD,gcw+64,gcb,xE,0);
    // support 2 chain (0.5*adj, batched)
    k_nconv<<<dim3(8,lo,16),dim3(256),0,stream>>>(alt,adjb,xC,lo,1);
    k_acc<<<dim3(2,lo,512),dim3(256),0,stream>>>(xC,gcw+96,gcb,xE,0);
    k_nconv<<<dim3(8,lo,16),dim3(256),0,stream>>>(xC,adjb,xD,lo,1);
    k_final<<<dim3(2,lo,512),dim3(256),0,stream>>>(xD,gcw+128,xE,xcur,alt,d);

    float* tmp=xcur; xcur=alt; alt=tmp;
  }

  k_end1<<<dim3(2,512,16),dim3(256),0,stream>>>(skip,end1_w,end1_b,adjb);
  k_end2<<<dim3(2,12,16),dim3(256),0,stream>>>(adjb,end2_w,end2_b,(float*)d_out);
}

// Round 2
// 2380.712 us; speedup vs baseline: 1.0826x; 1.0826x over previous
//
#include <hip/hip_runtime.h>
#include <cstdint>
#include <math.h>

typedef unsigned short ushort_t;
typedef __bf16 bf16x8 __attribute__((ext_vector_type(8)));
typedef float f32x4 __attribute__((ext_vector_type(4)));

#define BNSCALE 0.9999950000374998f

__device__ __forceinline__ ushort_t f2b(float x){
  union { float f; uint32_t u; } v; v.f = x;
  uint32_t u = v.u;
  u = u + 0x7fffu + ((u >> 16) & 1u);
  return (ushort_t)(u >> 16);
}
__device__ __forceinline__ float b2f(ushort_t h){
  union { float f; uint32_t u; } v; v.u = ((uint32_t)h) << 16; return v.f;
}

__device__ __forceinline__ uint32_t rotl32(uint32_t x, int d){ return (x<<d)|(x>>(32-d)); }

__device__ __forceinline__ void threefry2x32(uint32_t& x0, uint32_t& x1){
  const uint32_t ks0=0u, ks1=42u, ks2=42u^0x1BD11BDAu;
  x0+=ks0; x1+=ks1;
  x0+=x1; x1=rotl32(x1,13); x1^=x0;
  x0+=x1; x1=rotl32(x1,15); x1^=x0;
  x0+=x1; x1=rotl32(x1,26); x1^=x0;
  x0+=x1; x1=rotl32(x1, 6); x1^=x0;
  x0+=ks1; x1+=ks2+1u;
  x0+=x1; x1=rotl32(x1,17); x1^=x0;
  x0+=x1; x1=rotl32(x1,29); x1^=x0;
  x0+=x1; x1=rotl32(x1,16); x1^=x0;
  x0+=x1; x1=rotl32(x1,24); x1^=x0;
  x0+=ks2; x1+=ks0+2u;
  x0+=x1; x1=rotl32(x1,13); x1^=x0;
  x0+=x1; x1=rotl32(x1,15); x1^=x0;
  x0+=x1; x1=rotl32(x1,26); x1^=x0;
  x0+=x1; x1=rotl32(x1, 6); x1^=x0;
  x0+=ks0; x1+=ks1+3u;
  x0+=x1; x1=rotl32(x1,17); x1^=x0;
  x0+=x1; x1=rotl32(x1,29); x1^=x0;
  x0+=x1; x1=rotl32(x1,16); x1^=x0;
  x0+=x1; x1=rotl32(x1,24); x1^=x0;
  x0+=ks1; x1+=ks2+4u;
  x0+=x1; x1=rotl32(x1,13); x1^=x0;
  x0+=x1; x1=rotl32(x1,15); x1^=x0;
  x0+=x1; x1=rotl32(x1,26); x1^=x0;
  x0+=x1; x1=rotl32(x1, 6); x1^=x0;
  x0+=ks2; x1+=ks0+5u;
}

// ---------------- start conv ----------------
__global__ void k_start(const float* __restrict__ hist, const float* __restrict__ sw,
                        const float* __restrict__ sb, float* __restrict__ x){
  int idx = blockIdx.x*256 + threadIdx.x;
  int n = idx & 511; int r = idx >> 9;
  int t = r % 13; r /= 13; int o = r & 31; int b = r >> 5;
  float acc = sb[o];
  if (t > 0){
    const float* h = hist + ((size_t)(b*12 + (t-1))*512 + n)*3;
    acc += h[0]*sw[o*2+0] + h[1]*sw[o*2+1];
  }
  x[idx] = acc;
}

// ---------------- nodevec graph ----------------
__global__ void k_gw_mm(const float* __restrict__ nv1, const float* __restrict__ nv2,
                        float* __restrict__ gw){
  int idx = blockIdx.x*256+threadIdx.x;
  int w = idx & 511, v = idx >> 9;
  float acc=0.f;
  #pragma unroll
  for (int k=0;k<64;k++) acc += nv1[v*64+k]*nv2[k*512+w];
  gw[idx]=acc;
}

__global__ void k_gw_sm(float* __restrict__ gw){
  int v = blockIdx.x; int tid=threadIdx.x;
  float a0 = fmaxf(gw[v*512+tid],0.f), a1=fmaxf(gw[v*512+256+tid],0.f);
  __shared__ float red[256];
  red[tid]=fmaxf(a0,a1); __syncthreads();
  for(int s=128;s>0;s>>=1){ if(tid<s) red[tid]=fmaxf(red[tid],red[tid+s]); __syncthreads(); }
  float m = red[0]; __syncthreads();
  float e0=expf(a0-m), e1=expf(a1-m);
  red[tid]=e0+e1; __syncthreads();
  for(int s=128;s>0;s>>=1){ if(tid<s) red[tid]+=red[tid+s]; __syncthreads(); }
  float inv = 1.0f/red[0];
  gw[v*512+tid]=e0*inv; gw[v*512+256+tid]=e1*inv;
}

// ---------------- embedding ----------------
__global__ void k_embed(const float* __restrict__ hist, const float* __restrict__ Ex1,
                        const float* __restrict__ node1, const float* __restrict__ TiD,
                        const float* __restrict__ DiW, float* __restrict__ e){
  int row = blockIdx.x; int b = row >> 9; int n = row & 511;
  int tid = threadIdx.x;
  __shared__ float fr[7];
  if (tid < 7){
    float re=0.f, im=0.f;
    for (int l=0;l<12;l++){
      float v = hist[((size_t)(b*12+l)*512+n)*3];
      float ang = -2.0f*3.14159265358979323846f*(float)(tid*l)/12.0f;
      re += v*cosf(ang); im += v*sinf(ang);
    }
    fr[tid]=sqrtf(re*re+im*im);
  }
  __syncthreads();
  float* er = e + (size_t)row*152;
  float acc=0.f;
  #pragma unroll
  for (int f=0;f<7;f++) acc += fr[f]*Ex1[f*64+tid];
  er[tid]=acc;
  er[64+tid]=node1[n*64+tid];
  if (tid<12){
    int it = (int)(hist[((size_t)(b*12+11)*512+n)*3+1]*288.0f);
    int id = (int)(hist[((size_t)(b*12+11)*512+n)*3+2]*7.0f);
    er[128+tid]=TiD[it*12+tid];
    er[140+tid]=DiW[id*12+tid];
  }
}

// ---------------- adp = e @ Wd[n], Wd read once ----------------
__global__ void k_adp(const float* __restrict__ e, const float* __restrict__ Wd,
                      float* __restrict__ adp){
  int n = blockIdx.x; int tid = threadIdx.x; // 128 threads
  __shared__ float es[16][152];
  for (int idx = tid; idx < 16*152; idx += 128){
    int r = idx / 152, q = idx - r*152;
    es[r][q] = e[((size_t)(r*512+n))*152 + q];
  }
  __syncthreads();
  const float* w = Wd + (size_t)n*152*128;
  float acc[16];
  #pragma unroll
  for (int r=0;r<16;r++) acc[r]=0.f;
  for (int q = 0; q < 152; q++){
    float wv = w[q*128 + tid];
    #pragma unroll
    for (int r = 0; r < 16; r++) acc[r] += es[r][q]*wv;
  }
  #pragma unroll
  for (int r=0;r<16;r++) adp[((size_t)(r*512+n))*128 + tid] = acc[r];
}

// ---------------- layernorm ----------------
__global__ void k_lnstats(const float* __restrict__ adp, float* __restrict__ stats){
  int b=blockIdx.x, tid=threadIdx.x;
  const float* p = adp + (size_t)b*65536;
  double s=0.0, s2=0.0;
  for(int i=tid;i<65536;i+=256){ float v=p[i]; s+=v; s2+=(double)v*v; }
  __shared__ double rs[256], rs2[256];
  rs[tid]=s; rs2[tid]=s2; __syncthreads();
  for(int k=128;k>0;k>>=1){ if(tid<k){rs[tid]+=rs[tid+k]; rs2[tid]+=rs2[tid+k];} __syncthreads(); }
  if(tid==0){ double mu=rs[0]/65536.0; double var=rs2[0]/65536.0 - mu*mu;
    stats[b*2]=(float)mu; stats[b*2+1]=(float)(1.0/sqrt(var+1e-8)); }
}

__global__ void k_lnapply(float* __restrict__ adp, const float* __restrict__ stats){
  int idx=blockIdx.x*256+threadIdx.x;
  int b = idx>>16;
  adp[idx]=(adp[idx]-stats[2*b])*stats[2*b+1];
}

// ---------------- t = adp @ Wxabs ----------------
__global__ void k_xw(const float* __restrict__ adp, const float* __restrict__ Wx,
                     float* __restrict__ t){
  int row=blockIdx.x; int tid=threadIdx.x;
  __shared__ float as[128];
  as[tid]=adp[(size_t)row*128+tid]; __syncthreads();
  float acc=0.f;
  #pragma unroll 8
  for(int k=0;k<128;k++) acc += as[k]*Wx[k*128+tid];
  t[(size_t)row*128+tid]=acc;
}

// ---------------- adj = relu(t @ adp^T) ----------------
__global__ __launch_bounds__(256) void k_adjmm(const float* __restrict__ T,
                        const float* __restrict__ P, float* __restrict__ adj){
  int b = blockIdx.z;
  int n0 = blockIdx.y*32, m0 = blockIdx.x*64;
  const float* Tb = T + (size_t)b*512*128;
  const float* Pb = P + (size_t)b*512*128;
  __shared__ float Ts[32][33];
  __shared__ float Ps[64][33];
  int tid=threadIdx.x; int tx=tid&15, ty=tid>>4;
  float acc[2][4]={};
  for(int k0=0;k0<128;k0+=32){
    for(int q=0;q<4;q++){ int idx=tid+q*256; int r=idx>>5, kk=idx&31; Ts[r][kk]=Tb[(size_t)(n0+r)*128+k0+kk]; }
    for(int q=0;q<8;q++){ int idx=tid+q*256; int r=idx>>5, kk=idx&31; Ps[r][kk]=Pb[(size_t)(m0+r)*128+k0+kk]; }
    __syncthreads();
    #pragma unroll
    for(int kk=0;kk<32;kk++){
      float t0=Ts[ty][kk], t1=Ts[ty+16][kk];
      float p0=Ps[tx*4+0][kk], p1=Ps[tx*4+1][kk], p2=Ps[tx*4+2][kk], p3=Ps[tx*4+3][kk];
      acc[0][0]+=t0*p0; acc[0][1]+=t0*p1; acc[0][2]+=t0*p2; acc[0][3]+=t0*p3;
      acc[1][0]+=t1*p0; acc[1][1]+=t1*p1; acc[1][2]+=t1*p2; acc[1][3]+=t1*p3;
    }
    __syncthreads();
  }
  for(int i2=0;i2<2;i2++){
    int n=n0+ty+16*i2;
    float4 o4=make_float4(fmaxf(acc[i2][0],0.f),fmaxf(acc[i2][1],0.f),
                          fmaxf(acc[i2][2],0.f),fmaxf(acc[i2][3],0.f));
    *(float4*)&adj[((size_t)b*512+n)*512+m0+tx*4]=o4;
  }
}

// ---------------- top-20 + mask + softmax, *0.5 folded ----------------
__global__ void k_topk(float* __restrict__ adj){
  const int row = blockIdx.x;
  const int tid = threadIdx.x;
  const uint32_t halfn = 2097152u;
  float a[8], v[8];
  const bool lowhalf = row < 4096;
  #pragma unroll
  for(int k=0;k<8;k++){
    int m = k*64+tid;
    uint32_t i = (uint32_t)row*512u + (uint32_t)m;
    uint32_t c0 = lowhalf ? i : i - halfn;
    uint32_t x0=c0, x1=c0+halfn;
    threefry2x32(x0,x1);
    uint32_t bits = lowhalf ? x0 : x1;
    float u = __uint_as_float((bits>>9)|0x3f800000u)-1.0f;
    a[k]=adj[(size_t)row*512+m];
    v[k]=a[k]+0.01f*u;
  }
  unsigned selmask=0u;
  for(int it=0; it<20; it++){
    float best=-1e30f; int bi=0x7fffffff;
    #pragma unroll
    for(int k=0;k<8;k++){
      if(!((selmask>>k)&1u)){
        int m=k*64+tid;
        if(v[k]>best || (v[k]==best && m<bi)){best=v[k]; bi=m;}
      }
    }
    #pragma unroll
    for(int off=32; off>=1; off>>=1){
      float ov=__shfl_xor(best,off); int oi=__shfl_xor(bi,off);
      if(ov>best || (ov==best && oi<bi)){best=ov; bi=oi;}
    }
    if((bi&63)==tid) selmask |= 1u<<(bi>>6);
  }
  float M=0.f;
  #pragma unroll
  for(int k=0;k<8;k++) if((selmask>>k)&1u) M=fmaxf(M,a[k]);
  #pragma unroll
  for(int off=32;off>=1;off>>=1) M=fmaxf(M,__shfl_xor(M,off));
  float S=0.f;
  #pragma unroll
  for(int k=0;k<8;k++) S += expf((((selmask>>k)&1u)? a[k]:0.f) - M);
  #pragma unroll
  for(int off=32;off>=1;off>>=1) S += __shfl_xor(S,off);
  float inv = 0.5f/S;
  #pragma unroll
  for(int k=0;k<8;k++){
    int m=k*64+tid;
    adj[(size_t)row*512+m] = expf((((selmask>>k)&1u)? a[k]:0.f)-M)*inv;
  }
}

// ---------------- fp32 -> split bf16 (elementwise) ----------------
__global__ void k_split(const float* __restrict__ src, ushort_t* __restrict__ hi,
                        ushort_t* __restrict__ lo, int count){
  int i = blockIdx.x*256+threadIdx.x;
  if (i < count){
    float v = src[i];
    ushort_t h = f2b(v);
    hi[i] = h;
    if (lo) lo[i] = f2b(v - b2f(h));
  }
}

// ---------------- fp32 -> split bf16 with transpose ----------------
__global__ void k_splitT(const float* __restrict__ src, long sBS,
                         ushort_t* __restrict__ hi, long hBS, int hRS,
                         ushort_t* __restrict__ lo, long lBS, int lRS){
  int b = blockIdx.z;
  int c0 = blockIdx.x*32, r0 = blockIdx.y*32;
  __shared__ float tile[32][33];
  int tx = threadIdx.x & 31, ty = threadIdx.x >> 5;
  for (int q = 0; q < 4; q++)
    tile[ty+q*8][tx] = src[b*sBS + (size_t)(r0+ty+q*8)*512 + c0+tx];
  __syncthreads();
  for (int q = 0; q < 4; q++){
    int cc = c0+ty+q*8, rr = r0+tx;
    float v = tile[tx][ty+q*8];
    ushort_t h = f2b(v);
    hi[b*hBS + (size_t)cc*hRS + rr] = h;
    if (lo) lo[b*lBS + (size_t)cc*lRS + rr] = f2b(v - b2f(h));
  }
}

// ---------------- MFMA split-bf16 GEMM ----------------
// D[r][n] = sum_k A[r][k]*B[k][n]; A rows K-contig (Ah/Al), B stored transposed
// (Bh[n][k] K-contig). NTERM: 3 = ah*bh+al*bh+ah*bl; 2 = ah*bh+al*bh; 1 = ah*bh.
// CMODE 0: C[ofs] = (C[ofs]+acc)*cscale (fp32 RMW); CMODE 1: split-write Ch/Cl.
template<int CMODE, int NTERM>
__global__ __launch_bounds__(64,2) void k_gemm(
    const ushort_t* __restrict__ Ah, const ushort_t* __restrict__ Al,
    const ushort_t* __restrict__ Bh, const ushort_t* __restrict__ Bl,
    float* __restrict__ C, ushort_t* __restrict__ Ch, ushort_t* __restrict__ Cl,
    int M, int lo, int aOS, int aTS, long aBS,
    int bRS, long bBS, int blRS, long blBS,
    long cBS, int cOS, int cTS, int cRS,
    int K, float cscale){
  int b = blockIdx.z;
  int r0 = blockIdx.x*64, n0 = blockIdx.y*64;
  int l = threadIdx.x, lr = l & 15, kg = l >> 4;
  long aoff[4], boffh[4], boffl[4];
  #pragma unroll
  for (int ms = 0; ms < 4; ms++){
    int r = r0 + ms*16 + lr; if (r >= M) r = 0;
    int o = r / lo, t = r - o*lo;
    aoff[ms] = (long)b*aBS + (long)o*aOS + (long)t*aTS + kg*8;
  }
  #pragma unroll
  for (int ns = 0; ns < 4; ns++){
    int m = n0 + ns*16 + lr;
    boffh[ns] = (long)b*bBS + (long)m*bRS + kg*8;
    boffl[ns] = (long)b*blBS + (long)m*blRS + kg*8;
  }
  f32x4 acc[4][4];
  #pragma unroll
  for (int ms = 0; ms < 4; ms++)
    #pragma unroll
    for (int ns = 0; ns < 4; ns++) acc[ms][ns] = (f32x4){0.f,0.f,0.f,0.f};
  for (int k0 = 0; k0 < K; k0 += 32){
    bf16x8 bhv[4], blv[4];
    #pragma unroll
    for (int ns = 0; ns < 4; ns++){
      bhv[ns] = *(const bf16x8*)(Bh + boffh[ns] + k0);
      if (NTERM == 3) blv[ns] = *(const bf16x8*)(Bl + boffl[ns] + k0);
    }
    #pragma unroll
    for (int ms = 0; ms < 4; ms++){
      bf16x8 ahv = *(const bf16x8*)(Ah + aoff[ms] + k0);
      bf16x8 alv;
      if (NTERM >= 2) alv = *(const bf16x8*)(Al + aoff[ms] + k0);
      #pragma unroll
      for (int ns = 0; ns < 4; ns++){
        acc[ms][ns] = __builtin_amdgcn_mfma_f32_16x16x32_bf16(ahv, bhv[ns], acc[ms][ns], 0, 0, 0);
        if (NTERM >= 2)
          acc[ms][ns] = __builtin_amdgcn_mfma_f32_16x16x32_bf16(alv, bhv[ns], acc[ms][ns], 0, 0, 0);
        if (NTERM == 3)
          acc[ms][ns] = __builtin_amdgcn_mfma_f32_16x16x32_bf16(ahv, blv[ns], acc[ms][ns], 0, 0, 0);
      }
    }
  }
  #pragma unroll
  for (int ms = 0; ms < 4; ms++){
    #pragma unroll
    for (int rg = 0; rg < 4; rg++){
      int r = r0 + ms*16 + kg*4 + rg;
      if (r >= M) continue;
      int o = r / lo, t = r - o*lo;
      #pragma unroll
      for (int ns = 0; ns < 4; ns++){
        int n = n0 + ns*16 + lr;
        float v = acc[ms][ns][rg];
        if (CMODE == 0){
          long ofs = (long)b*cBS + (long)o*cOS + (long)t*cTS + n;
          C[ofs] = (C[ofs] + v)*cscale;
        } else {
          long ofs = (long)b*cBS + (long)r*cRS + n;
          ushort_t hv = f2b(v);
          Ch[ofs] = hv;
          if (Cl) Cl[ofs] = f2b(v - b2f(hv));
        }
      }
    }
  }
}

// ---------------- fused tconv + channel-mix + base ----------------
// pass 0: compute fg = tanh(filt)*sig(gate), write fg/fgL, base=W0*fg+bias+res -> xnew,
//         and Z group 0. pass>=1: read fg, write Z group `pass`.
__global__ __launch_bounds__(256,2) void k_mix(const float* __restrict__ x,
    const float* __restrict__ fw, const float* __restrict__ fb,
    const float* __restrict__ gwv, const float* __restrict__ gb,
    const float* __restrict__ gcw, const float* __restrict__ gcb,
    ushort_t* __restrict__ Zh, ushort_t* __restrict__ Zl,
    float* __restrict__ xnew, float* __restrict__ fg_full, float* __restrict__ fgL,
    int d, int lo, int pass){
  __shared__ float MWs[1024];
  __shared__ float FWs[2048], GWs[2048], W0s[1024];
  __shared__ float fbs[32], gbs[32], gcbs[32];
  int tid = threadIdx.x;
  int t = blockIdx.y, b = blockIdx.z;
  int n = blockIdx.x*256 + tid;
  int mwoff = (pass+1)*32;
  for (int idx = tid; idx < 1024; idx += 256) MWs[idx] = gcw[(idx>>5)*160 + mwoff + (idx&31)];
  if (pass == 0){
    for (int idx = tid; idx < 2048; idx += 256){ FWs[idx] = fw[idx]; GWs[idx] = gwv[idx]; }
    for (int idx = tid; idx < 1024; idx += 256) W0s[idx] = gcw[(idx>>5)*160 + (idx&31)];
    if (tid < 32){ fbs[tid]=fb[tid]; gbs[tid]=gb[tid]; gcbs[tid]=gcb[tid]; }
  }
  __syncthreads();
  float fgv[32];
  size_t pofs = ((size_t)b*32*13 + t)*512 + n;
  if (pass == 0){
    float xv[32], xv2[32];
    #pragma unroll
    for (int c = 0; c < 32; c++){ xv[c] = x[pofs + c*6656]; xv2[c] = x[pofs + c*6656 + d*512]; }
    #pragma unroll
    for (int o = 0; o < 32; o++){
      float f = fbs[o], g = gbs[o];
      #pragma unroll
      for (int c = 0; c < 32; c++){
        float2 wf = *(const float2*)&FWs[(o*32+c)*2];
        float2 wg = *(const float2*)&GWs[(o*32+c)*2];
        f += xv[c]*wf.x + xv2[c]*wf.y;
        g += xv[c]*wg.x + xv2[c]*wg.y;
      }
      f = fminf(f, 15.f);
      float e2 = __expf(2.f*f);
      float th = (e2 - 1.f) / (e2 + 1.f);
      float sg = 1.f / (1.f + __expf(-g));
      fgv[o] = th * sg;
    }
    #pragma unroll
    for (int o = 0; o < 32; o++){
      float bs = gcbs[o] + xv2[o];
      #pragma unroll
      for (int c = 0; c < 32; c++) bs += W0s[o*32+c]*fgv[c];
      xnew[pofs + o*6656] = bs;
    }
    #pragma unroll
    for (int o = 0; o < 32; o++) fg_full[pofs + o*6656] = fgv[o];
    if (t == lo-1){
      #pragma unroll
      for (int o = 0; o < 32; o++) fgL[((size_t)b*32+o)*512 + n] = fgv[o];
    }
  } else {
    #pragma unroll
    for (int o = 0; o < 32; o++) fgv[o] = fg_full[pofs + o*6656];
  }
  #pragma unroll
  for (int o = 0; o < 32; o++){
    float z = 0.f;
    #pragma unroll
    for (int c = 0; c < 32; c++) z += MWs[o*32+c]*fgv[c];
    ushort_t h = f2b(z);
    Zh[pofs + o*6656] = h;
    Zl[pofs + o*6656] = f2b(z - b2f(h));
  }
}

// ---------------- skip accumulation (LDS-tiled) ----------------
__global__ void k_skipacc(const float* __restrict__ fgL, const float* __restrict__ sw,
                          const float* __restrict__ sb, float* __restrict__ skip){
  int b = blockIdx.y; int n0 = blockIdx.x*64;
  int tid = threadIdx.x; int col = tid & 63; int q = tid >> 6;
  __shared__ float fgls[32][65];
  for (int idx = tid; idx < 2048; idx += 256){
    int c = idx >> 6, j = idx & 63;
    fgls[c][j] = fgL[((size_t)b*32+c)*512 + n0 + j];
  }
  __syncthreads();
  for (int s = q*64; s < q*64+64; s++){
    float acc = sb[s];
    #pragma unroll
    for (int c = 0; c < 32; c++) acc += sw[s*32+c]*fgls[c][col];
    skip[((size_t)b*256+s)*512 + n0+col] += acc;
  }
}

// ---------------- end1: tiled GEMM with relu in/out ----------------
__global__ __launch_bounds__(256) void k_end1t(const float* __restrict__ skip,
                        const float* __restrict__ w, const float* __restrict__ bias,
                        float* __restrict__ h){
  int b = blockIdx.z; int e0 = blockIdx.y*32; int n0 = blockIdx.x*64;
  __shared__ float Ws_[32][33];
  __shared__ float Ss_[32][64];
  int tid = threadIdx.x, tx = tid&15, ty = tid>>4;
  float acc[2][4] = {};
  for (int k0 = 0; k0 < 256; k0 += 32){
    for (int q2 = 0; q2 < 4; q2++){ int idx = tid + q2*256; int r = idx>>5, kk = idx&31;
      Ws_[r][kk] = w[(size_t)(e0+r)*256 + k0+kk]; }
    for (int q2 = 0; q2 < 8; q2++){ int idx = tid + q2*256; int r = idx>>6, ww = idx&63;
      Ss_[r][ww] = fmaxf(skip[(size_t)b*131072 + (size_t)(k0+r)*512 + n0+ww], 0.f); }
    __syncthreads();
    #pragma unroll
    for (int kk = 0; kk < 32; kk++){
      float t0 = Ws_[ty][kk], t1 = Ws_[ty+16][kk];
      float4 b4 = *(float4*)&Ss_[kk][tx*4];
      acc[0][0]+=t0*b4.x; acc[0][1]+=t0*b4.y; acc[0][2]+=t0*b4.z; acc[0][3]+=t0*b4.w;
      acc[1][0]+=t1*b4.x; acc[1][1]+=t1*b4.y; acc[1][2]+=t1*b4.z; acc[1][3]+=t1*b4.w;
    }
    __syncthreads();
  }
  for (int i2 = 0; i2 < 2; i2++){
    int e = e0 + ty + 16*i2;
    float bb = bias[e];
    float4 o4 = make_float4(fmaxf(acc[i2][0]+bb,0.f), fmaxf(acc[i2][1]+bb,0.f),
                            fmaxf(acc[i2][2]+bb,0.f), fmaxf(acc[i2][3]+bb,0.f));
    *(float4*)&h[(size_t)b*262144 + (size_t)e*512 + n0 + tx*4] = o4;
  }
}

__global__ void k_end2(const float* __restrict__ h, const float* __restrict__ w,
                       const float* __restrict__ bias, float* __restrict__ out){
  int n = blockIdx.x*256+threadIdx.x; int o=blockIdx.y; int b=blockIdx.z;
  float acc=bias[o];
  const float* hb=h + (size_t)b*262144 + n;
  #pragma unroll 8
  for (int e=0;e<512;e++) acc += w[o*512+e]*hb[(size_t)e*512];
  out[((size_t)b*12+o)*512+n]=acc;
}

extern "C" void kernel_launch(void* const* d_in, const int* in_sizes, int n_in,
                              void* d_out, int out_size, void* d_ws, size_t ws_size,
                              hipStream_t stream) {
  (void)in_sizes; (void)n_in; (void)out_size;
  const float* hist   =(const float*)d_in[0];
  const float* start_w=(const float*)d_in[1];
  const float* start_b=(const float*)d_in[2];
  const float* filt_w =(const float*)d_in[3];
  const float* filt_b =(const float*)d_in[4];
  const float* gate_w =(const float*)d_in[5];
  const float* gate_b =(const float*)d_in[6];
  const float* skip_w =(const float*)d_in[7];
  const float* skip_b =(const float*)d_in[8];
  const float* gconv_w=(const float*)d_in[9];
  const float* gconv_b=(const float*)d_in[10];
  const float* end1_w =(const float*)d_in[11];
  const float* end1_b =(const float*)d_in[12];
  const float* end2_w =(const float*)d_in[13];
  const float* end2_b =(const float*)d_in[14];
  const float* Ex1    =(const float*)d_in[15];
  const float* node1  =(const float*)d_in[16];
  const float* Wd     =(const float*)d_in[17];
  const float* Wxabs  =(const float*)d_in[18];
  const float* TiD    =(const float*)d_in[19];
  const float* DiW    =(const float*)d_in[20];
  const float* nv1    =(const float*)d_in[21];
  const float* nv2    =(const float*)d_in[22];

  char* ws = (char*)d_ws;
  const size_t needed = 91226368;
  if (ws_size < needed) return;

  float*    xA     = (float*)(ws + 0);            // 13,631,488 B
  float*    skip   = (float*)(ws + 13631488);     //  8,388,608
  float*    fgL    = (float*)(ws + 22020096);     //  1,048,576
  float*    stats  = (float*)(ws + 23068672);     //  256
  float*    fg     = (float*)(ws + 23068928);     // 13,631,488
  ushort_t* PtA_hi = (ushort_t*)(ws + 36700416);  //  1,048,576  [m][2][512]
  ushort_t* PtA_lo = (ushort_t*)(ws + 37748992);  //  1,048,576
  ushort_t* PtB_hi = (ushort_t*)(ws + 38797568);  // 16,777,216  [b][m][2][512]
  ushort_t* PtB_lo = (ushort_t*)(ws + 55574784);  //  8,388,608  [b][m][512] (g2 only)
  char*     region = ws + 63963392;               // 27,262,976
  float*    xB     = (float*)(region);
  ushort_t* Zh     = (ushort_t*)(region + 13631488);
  ushort_t* Zl     = (ushort_t*)(region + 20447232);
  // prologue aliases inside region:
  float*    gwb    = (float*)(region);
  ushort_t* gws_hi = (ushort_t*)(region + 1048576);
  ushort_t* gws_lo = (ushort_t*)(region + 1572864);
  float*    adjb   = (float*)(region);
  float*    adp    = (float*)(region + 16777216);
  float*    ebuf   = (float*)(region + 20971520);
  float*    xw     = (float*)(region + 20971520);
  ushort_t* adjhi  = (ushort_t*)(region + 16777216);
  float*    hbuf   = (float*)(region);

  k_start<<<dim3(13312),dim3(256),0,stream>>>(hist,start_w,start_b,xA);

  // ---- graph support A = gwadp, and A^2 (shared across batch) ----
  k_gw_mm<<<dim3(1024),dim3(256),0,stream>>>(nv1,nv2,gwb);
  k_gw_sm<<<dim3(512),dim3(256),0,stream>>>(gwb);
  k_split<<<dim3(1024),dim3(256),0,stream>>>(gwb, gws_hi, gws_lo, 262144);
  k_splitT<<<dim3(16,16,1),dim3(256),0,stream>>>(gwb, 0, PtA_hi, 0, 1024, PtA_lo, 0, 1024);
  k_gemm<1,3><<<dim3(8,8,1),dim3(64),0,stream>>>(
      PtA_hi, PtA_lo, gws_hi, gws_lo, nullptr, PtA_hi+512, PtA_lo+512,
      512, 512, 0, 1024, 0,  512, 0, 512, 0,  0, 0, 0, 1024, 512, 1.0f);

  // ---- data-dependent support B = 0.5*softmax(mask(adj)) and B^2 ----
  k_embed<<<dim3(8192),dim3(64),0,stream>>>(hist,Ex1,node1,TiD,DiW,ebuf);
  k_adp<<<dim3(512),dim3(128),0,stream>>>(ebuf,Wd,adp);
  k_lnstats<<<dim3(16),dim3(256),0,stream>>>(adp,stats);
  k_lnapply<<<dim3(4096),dim3(256),0,stream>>>(adp,stats);
  k_xw<<<dim3(8192),dim3(128),0,stream>>>(adp,Wxabs,xw);
  k_adjmm<<<dim3(8,16,16),dim3(256),0,stream>>>(xw,adp,adjb);
  k_topk<<<dim3(8192),dim3(64),0,stream>>>(adjb);
  k_splitT<<<dim3(16,16,16),dim3(256),0,stream>>>(adjb, 262144, PtB_hi, 524288, 1024,
                                                  PtB_lo, 262144, 512);
  k_split<<<dim3(16384),dim3(256),0,stream>>>(adjb, adjhi, nullptr, 4194304);
  k_gemm<1,1><<<dim3(8,8,16),dim3(64),0,stream>>>(
      PtB_hi, PtB_hi, adjhi, adjhi, nullptr, PtB_hi+512, nullptr,
      512, 512, 0, 1024, 524288,  512, 262144, 512, 262144,  524288, 0, 0, 1024, 512, 1.0f);

  hipMemsetAsync(skip, 0, (size_t)16*256*512*sizeof(float), stream);

  const int lin[8]={13,12,10,9,7,6,4,3};
  const int dil[8]={1,2,1,2,1,2,1,2};
  float* xcur=xA; float* alt=xB;
  for (int i=0;i<8;i++){
    int d=dil[i], lo=lin[i]-d;
    const float* fwp=filt_w+(size_t)i*2048; const float* fbp=filt_b+i*32;
    const float* gwp=gate_w+(size_t)i*2048; const float* gbp=gate_b+i*32;
    const float* swp=skip_w+(size_t)i*8192; const float* sbp=skip_b+i*256;
    const float* gcwp=gconv_w+(size_t)i*5120; const float* gcbp=gconv_b+i*32;
    int M = 32*lo, Mt = (M+63)/64;

    k_mix<<<dim3(2,lo,16),dim3(256),0,stream>>>(xcur,fwp,fbp,gwp,gbp,gcwp,gcbp,
        Zh,Zl,alt,fg,fgL,d,lo,0);
    k_skipacc<<<dim3(8,16),dim3(256),0,stream>>>(fgL,swp,sbp,skip);

    if (i < 7){
      // pass 0: A
      k_gemm<0,3><<<dim3(Mt,8,16),dim3(64),0,stream>>>(
          Zh, Zl, PtA_hi, PtA_lo, alt, nullptr, nullptr,
          M, lo, 6656, 512, 212992,  1024, 0, 1024, 0,  212992, 6656, 512, 0, 512, 1.0f);
      // pass 1: A^2
      k_mix<<<dim3(2,lo,16),dim3(256),0,stream>>>(xcur,fwp,fbp,gwp,gbp,gcwp,gcbp,
          Zh,Zl,alt,fg,fgL,d,lo,1);
      k_gemm<0,3><<<dim3(Mt,8,16),dim3(64),0,stream>>>(
          Zh, Zl, PtA_hi+512, PtA_lo+512, alt, nullptr, nullptr,
          M, lo, 6656, 512, 212992,  1024, 0, 1024, 0,  212992, 6656, 512, 0, 512, 1.0f);
      // pass 2: B
      k_mix<<<dim3(2,lo,16),dim3(256),0,stream>>>(xcur,fwp,fbp,gwp,gbp,gcwp,gcbp,
          Zh,Zl,alt,fg,fgL,d,lo,2);
      k_gemm<0,3><<<dim3(Mt,8,16),dim3(64),0,stream>>>(
          Zh, Zl, PtB_hi, PtB_lo, alt, nullptr, nullptr,
          M, lo, 6656, 512, 212992,  1024, 524288, 512, 262144,  212992, 6656, 512, 0, 512, 1.0f);
      // pass 3: B^2 (hi-only B-operand) + BN scale
      k_mix<<<dim3(2,lo,16),dim3(256),0,stream>>>(xcur,fwp,fbp,gwp,gbp,gcwp,gcbp,
          Zh,Zl,alt,fg,fgL,d,lo,3);
      k_gemm<0,2><<<dim3(Mt,8,16),dim3(64),0,stream>>>(
          Zh, Zl, PtB_hi+512, PtB_hi+512, alt, nullptr, nullptr,
          M, lo, 6656, 512, 212992,  1024, 524288, 1024, 524288,  212992, 6656, 512, 0, 512, BNSCALE);
    }
    float* tmp=xcur; xcur=alt; alt=tmp;
  }

  k_end1t<<<dim3(8,16,16),dim3(256),0,stream>>>(skip,end1_w,end1_b,hbuf);
  k_end2<<<dim3(2,12,16),dim3(256),0,stream>>>(hbuf,end2_w,end2_b,(float*)d_out);
}